// Round 13
// baseline (82.187 us; speedup 1.0000x reference)
//
#include <hip/hip_runtime.h>
#include <stdint.h>

#define NB 64
#define NN 1024
#define CDIM 512
#define KK 64

typedef __attribute__((ext_vector_type(4))) float f32x4;
typedef __attribute__((ext_vector_type(8))) short short8;

__device__ __forceinline__ unsigned short f2bf(float f) {
  unsigned int u = __float_as_uint(f);
  return (unsigned short)((u + 0x7fffu + ((u >> 16) & 1u)) >> 16);
}
__device__ __forceinline__ float bf2f(unsigned short h) {
  return __uint_as_float(((unsigned int)h) << 16);
}

__device__ __forceinline__ void lgkm_barrier() {
  // raw workgroup barrier that does NOT drain vmcnt (k2 only)
  asm volatile("s_waitcnt lgkmcnt(0)" ::: "memory");
  __builtin_amdgcn_sched_barrier(0);
  __builtin_amdgcn_s_barrier();
}

// ---------------- K0: centers fp32 -> bf16 ----------------
__global__ __launch_bounds__(256) void k0_cvt(const float* __restrict__ cc,
                                              unsigned short* __restrict__ ccb) {
  int i = blockIdx.x * 256 + threadIdx.x;   // grid sized exactly KK*CDIM/256
  ccb[i] = f2bf(cc[i]);
}

// ---- K1: logits + softmax + a^T + xT — wave = 32n x 512c, DIRECT xT stores ----
// grid: (8, 64 b) = 512 blocks, 256 thr = 4 independent waves (8 waves/CU).
// Wave owns 32-n chunk nc = bx*4+w (rows n0 + tn*16 + lr, tn in {0,1}), ALL c.
// Per 64-c step: 8 f32x4 x-loads (128 B/lane in flight), f2bf, 16 MFMA,
// lane-pair shuffle pack, 16 DIRECT global u32 stores to flat xT[b][c][n2].
// No LDS in the hot loop, no block syncs anywhere, no partial-acc exchange.
// Epilogue: in-register softmax over full k; a^T pack via tiny per-wave slab.
__global__ __launch_bounds__(256, 2) void k1_assign(const float* __restrict__ x,
    const unsigned short* __restrict__ ccb, unsigned int* __restrict__ a_t32,
    unsigned int* __restrict__ xT32) {
  const int b = blockIdx.y;
  const int tid = threadIdx.x;
  const int w = tid >> 6;
  const int l = tid & 63;
  const int lr = l & 15;
  const int lg = l >> 4;
  const int nc = (blockIdx.x << 2) + w;   // 32-n chunk id in [0,32)
  const int n0 = nc << 5;
  const int codd = l & 1;

  __shared__ unsigned int asw_all[4][64 * 17];   // 4.3 KB per wave (epilogue)
  unsigned int* asw = asw_all[w];

  const float* xr0 = x + ((size_t)b * NN + n0 + lr) * CDIM + (lg << 3);
  const float* xr1 = xr0 + (size_t)16 * CDIM;
  const unsigned short* cb = ccb + lr * CDIM + (lg << 3);
  // xT flat [b][c=512][n2=512 u32]; per-lane base folds b, n-pair, lg, codd
  unsigned int* xTb = xT32 + (((size_t)b) << 18) + (n0 >> 1) + (lr >> 1)
                      + (((size_t)((lg << 3) + codd)) << 9);

  f32x4 acc[2][4];   // [tn][tk]
  #pragma unroll
  for (int i = 0; i < 2; ++i)
    #pragma unroll
    for (int j = 0; j < 4; ++j) acc[i][j] = (f32x4){0.f, 0.f, 0.f, 0.f};

  #pragma unroll 2
  for (int step = 0; step < 8; ++step) {
    const int cs = step << 6;
    // 8 x-loads (2 tn x 2 c-subblocks x {xa,xb})
    f32x4 xa00 = *(const f32x4*)(xr0 + cs);
    f32x4 xb00 = *(const f32x4*)(xr0 + cs + 4);
    f32x4 xa01 = *(const f32x4*)(xr0 + cs + 32);
    f32x4 xb01 = *(const f32x4*)(xr0 + cs + 36);
    f32x4 xa10 = *(const f32x4*)(xr1 + cs);
    f32x4 xb10 = *(const f32x4*)(xr1 + cs + 4);
    f32x4 xa11 = *(const f32x4*)(xr1 + cs + 32);
    f32x4 xb11 = *(const f32x4*)(xr1 + cs + 36);
    short8 af[2][2];
    #pragma unroll
    for (int tn = 0; tn < 2; ++tn) {
      #pragma unroll
      for (int sub = 0; sub < 2; ++sub) {
        const f32x4 xa = tn == 0 ? (sub == 0 ? xa00 : xa01)
                                 : (sub == 0 ? xa10 : xa11);
        const f32x4 xb = tn == 0 ? (sub == 0 ? xb00 : xb01)
                                 : (sub == 0 ? xb10 : xb11);
        short8 t;
        t[0] = (short)f2bf(xa[0]); t[1] = (short)f2bf(xa[1]);
        t[2] = (short)f2bf(xa[2]); t[3] = (short)f2bf(xa[3]);
        t[4] = (short)f2bf(xb[0]); t[5] = (short)f2bf(xb[1]);
        t[6] = (short)f2bf(xb[2]); t[7] = (short)f2bf(xb[3]);
        af[tn][sub] = t;
      }
    }
    // cc frags (L1/L2-hot)
    #pragma unroll
    for (int tk = 0; tk < 4; ++tk) {
      short8 bq0 = *(const short8*)(cb + tk * 16 * CDIM + cs);
      short8 bq1 = *(const short8*)(cb + tk * 16 * CDIM + cs + 32);
      acc[0][tk] = __builtin_amdgcn_mfma_f32_16x16x32_bf16(af[0][0], bq0, acc[0][tk], 0, 0, 0);
      acc[0][tk] = __builtin_amdgcn_mfma_f32_16x16x32_bf16(af[0][1], bq1, acc[0][tk], 0, 0, 0);
      acc[1][tk] = __builtin_amdgcn_mfma_f32_16x16x32_bf16(af[1][0], bq0, acc[1][tk], 0, 0, 0);
      acc[1][tk] = __builtin_amdgcn_mfma_f32_16x16x32_bf16(af[1][1], bq1, acc[1][tk], 0, 0, 0);
    }
    // xT emit: lane-pair (n, n^1) shuffle pack -> DIRECT global u32 stores.
    // store row c = cs + sub*32 + lg*8 + 2q + codd, col n-pair offset tn*8.
    #pragma unroll
    for (int tn = 0; tn < 2; ++tn) {
      #pragma unroll
      for (int sub = 0; sub < 2; ++sub) {
        #pragma unroll
        for (int q = 0; q < 4; ++q) {
          unsigned int own = ((const unsigned int*)&af[tn][sub])[q];
          unsigned int oth = (unsigned int)__shfl_xor((int)own, 1);
          unsigned int v = codd ? ((oth >> 16) | (own & 0xffff0000u))
                                : ((own & 0xffffu) | (oth << 16));
          xTb[(((size_t)(cs + (sub << 5) + (q << 1))) << 9) + (tn << 3)] = v;
        }
      }
    }
  }

  // ---- in-register softmax over full k (4 tk x 16 lr), per tn/j ----
  #pragma unroll
  for (int tn = 0; tn < 2; ++tn) {
    #pragma unroll
    for (int j = 0; j < 4; ++j) {
      float m = fmaxf(fmaxf(acc[tn][0][j], acc[tn][1][j]),
                      fmaxf(acc[tn][2][j], acc[tn][3][j]));
      m = fmaxf(m, __shfl_xor(m, 1));
      m = fmaxf(m, __shfl_xor(m, 2));
      m = fmaxf(m, __shfl_xor(m, 4));
      m = fmaxf(m, __shfl_xor(m, 8));
      float e0 = __expf(acc[tn][0][j] - m);
      float e1 = __expf(acc[tn][1][j] - m);
      float e2 = __expf(acc[tn][2][j] - m);
      float e3 = __expf(acc[tn][3][j] - m);
      float s = e0 + e1 + e2 + e3;
      s += __shfl_xor(s, 1); s += __shfl_xor(s, 2);
      s += __shfl_xor(s, 4); s += __shfl_xor(s, 8);
      float inv = 1.0f / s;
      acc[tn][0][j] = e0 * inv;
      acc[tn][1][j] = e1 * inv;
      acc[tn][2][j] = e2 * inv;
      acc[tn][3][j] = e3 * inv;
    }
  }
  // a^T pack into per-wave slab: n-pair (2jp,2jp+1) same-lane, col tn*8+lg*2+jp
  #pragma unroll
  for (int tn = 0; tn < 2; ++tn)
    #pragma unroll
    for (int tk = 0; tk < 4; ++tk)
      #pragma unroll
      for (int jp = 0; jp < 2; ++jp) {
        unsigned int v = (unsigned int)f2bf(acc[tn][tk][2 * jp]) |
                         ((unsigned int)f2bf(acc[tn][tk][2 * jp + 1]) << 16);
        asw[((tk << 4) + lr) * 17 + (tn << 3) + (lg << 1) + jp] = v;
      }
  // drain: a_t flat [b][k=64][n2=512 u32]; 4 k-rows x 16 u32 per instr
  #pragma unroll
  for (int i = 0; i < 16; ++i) {
    const int k = (i << 2) + (l >> 4);
    const int np = l & 15;
    a_t32[(((size_t)((b << 6) + k)) << 9) + (n0 >> 1) + np] = asw[k * 17 + np];
  }
}

// ---- K2: agg = a^T x via MFMA; FLAT inputs; a_sum computed in-kernel ----
// grid: (8 c-slices, 64 b) = 512 blocks, 256 thr = 4 waves (k-split 16 each).
// Per 64-n chunk: stage xT[b][c0..c0+64)][it*32..+32] via 8 coalesced u32
// loads/thread into stride-38 LDS (dbuf); A-frags direct from a_t[b][k][n].
// T14 prefetch; raw lgkm-only barriers keep prefetched loads in flight.
#define XRS 38
__global__ __launch_bounds__(256) void k2_agg(
    const unsigned short* __restrict__ a_t, const unsigned int* __restrict__ xT32,
    const float* __restrict__ cc, float* __restrict__ out,
    float* __restrict__ sumsq) {
  const int b = blockIdx.y;
  const int c0 = blockIdx.x << 6;
  const int tid = threadIdx.x;
  const int w = tid >> 6;
  const int l = tid & 63;
  const int lr = l & 15;
  const int lg = l >> 4;

  __shared__ unsigned int xs[2][64 * XRS];  // 9728 B each
  __shared__ float red[4];

  f32x4 acc[4];
  #pragma unroll
  for (int i = 0; i < 4; ++i) acc[i] = (f32x4){0.f, 0.f, 0.f, 0.f};
  float ssum = 0.f;   // per-lane partial of a_sum[k=16w+lr]

  // A-frag pointer: row k = 16w + lr (1024 ush per row), n-offset lg*8
  const unsigned short* ap =
      a_t + (((size_t)((b << 6) + (w << 4) + lr)) << 10) + (lg << 3);
  // xT stage pointer: flat; c-row c0 + tid>>5 (512 u32 per row), col tid&31
  const unsigned int* xg =
      xT32 + (((size_t)((b << 9) + c0 + (tid >> 5))) << 9) + (tid & 31);

  // ---- prologue: stage chunk 0, load chunk-0 A-frags ----
  #pragma unroll
  for (int p = 0; p < 8; ++p) {
    const int f = (p << 8) + tid;
    xs[0][(f >> 5) * XRS + (f & 31)] = xg[(((size_t)p) << 12)];  // p*8 rows *512
  }
  short8 a_cur0 = *(const short8*)(ap);
  short8 a_cur1 = *(const short8*)(ap + 32);
  lgkm_barrier();

  for (int it = 0; it < 16; ++it) {
    const int cur = it & 1;
    unsigned int xr[8];
    short8 a_nxt0, a_nxt1;
    if (it < 15) {
      const int nu = (it + 1) << 5;   // u32 offset of next chunk
      #pragma unroll
      for (int p = 0; p < 8; ++p) xr[p] = xg[(((size_t)p) << 12) + nu];
      a_nxt0 = *(const short8*)(ap + ((it + 1) << 6));
      a_nxt1 = *(const short8*)(ap + ((it + 1) << 6) + 32);
    }
    #pragma unroll
    for (int i = 0; i < 8; ++i)
      ssum += bf2f((unsigned short)a_cur0[i]) + bf2f((unsigned short)a_cur1[i]);
    #pragma unroll
    for (int ns = 0; ns < 64; ns += 32) {
      const short8 af = ns == 0 ? a_cur0 : a_cur1;
      #pragma unroll
      for (int ct = 0; ct < 4; ++ct) {
        const int row = (ct << 4) + lr;
        const unsigned long long* bp = (const unsigned long long*)
            &xs[cur][row * XRS + (ns >> 1) + (lg << 2)];
        union { unsigned long long q[2]; short8 s; } u;
        u.q[0] = bp[0];
        u.q[1] = bp[1];
        acc[ct] = __builtin_amdgcn_mfma_f32_16x16x32_bf16(af, u.s, acc[ct], 0, 0, 0);
      }
    }
    if (it < 15) {
      #pragma unroll
      for (int p = 0; p < 8; ++p) {
        const int f = (p << 8) + tid;
        xs[cur ^ 1][(f >> 5) * XRS + (f & 31)] = xr[p];
      }
      a_cur0 = a_nxt0;
      a_cur1 = a_nxt1;
    }
    lgkm_barrier();
  }

  // a_sum reduce over lg groups; lane lr holds a_sum for k=16w+lr
  ssum += __shfl_xor(ssum, 16);
  ssum += __shfl_xor(ssum, 32);

  float lsum = 0.f;
  #pragma unroll
  for (int j = 0; j < 4; ++j) {
    const float asum_e = __shfl(ssum, (lg << 2) + j);   // a_sum[k=16w+lg*4+j]
    #pragma unroll
    for (int ct = 0; ct < 4; ++ct) {
      int k = (w << 4) + (lg << 2) + j;
      int c = c0 + (ct << 4) + lr;
      float v = acc[ct][j] - asum_e * cc[k * CDIM + c];
      out[((size_t)b << 15) + (k << 9) + c] = v;
      lsum += v * v;
    }
  }
  lsum += __shfl_xor(lsum, 1);  lsum += __shfl_xor(lsum, 2);
  lsum += __shfl_xor(lsum, 4);  lsum += __shfl_xor(lsum, 8);
  lsum += __shfl_xor(lsum, 16); lsum += __shfl_xor(lsum, 32);
  if (l == 0) red[w] = lsum;
  __syncthreads();
  if (tid == 0) atomicAdd(&sumsq[b], red[0] + red[1] + red[2] + red[3]);
}

// ---------------- K3: l2 normalize per batch ----------------
__global__ __launch_bounds__(256) void k3_norm(float* __restrict__ out,
                                               const float* __restrict__ sumsq) {
  int idx = blockIdx.x * 256 + threadIdx.x;   // grid exact: 2048*256 = 2M/4
  int b = idx >> 13;                          // 8192 float4 per batch
  float s = sumsq[b];
  float scale = 1.0f / sqrtf(fmaxf(s, 1e-12f));
  f32x4* io = (f32x4*)out;
  f32x4 v = io[idx];
  v[0] *= scale; v[1] *= scale; v[2] *= scale; v[3] *= scale;
  io[idx] = v;
}

extern "C" void kernel_launch(void* const* d_in, const int* in_sizes, int n_in,
                              void* d_out, int out_size, void* d_ws, size_t ws_size,
                              hipStream_t stream) {
  const float* x  = (const float*)d_in[0];
  const float* cc = (const float*)d_in[1];
  float* out = (float*)d_out;
  char* ws = (char*)d_ws;
  // ws: [a_t bf16 8MiB][ccb 64KiB][sumsq 256B] ... [xT 64MiB @16MiB]
  unsigned short* a_t = (unsigned short*)ws;
  unsigned int* a_t32 = (unsigned int*)ws;
  unsigned short* ccb = (unsigned short*)(ws + (8u << 20));
  float* sumsq = (float*)(ws + (8u << 20) + (64u << 10));
  unsigned int* xT32 = (unsigned int*)(ws + (16u << 20));

  (void)hipMemsetAsync(sumsq, 0, NB * 4, stream);
  k0_cvt<<<dim3((KK * CDIM) / 256), 256, 0, stream>>>(cc, ccb);
  k1_assign<<<dim3(8, NB), 256, 0, stream>>>(x, ccb, a_t32, xT32);
  k2_agg<<<dim3(8, NB), 256, 0, stream>>>(a_t, xT32, cc, out, sumsq);
  k3_norm<<<dim3(2048), 256, 0, stream>>>(out, sumsq);
}